// Round 1
// baseline (438.587 us; speedup 1.0000x reference)
//
#include <hip/hip_runtime.h>

#define NPTS 8192
#define KC   128
#define IFD  64
#define DL1  64
#define DL2  64
#define DL3  128
#define SPLITS 8
#define PPB  (NPTS/SPLITS)   // 1024 points per block

// ---------------------------------------------------------------------------
// Kernel 1: farthest point sampling (single block, matches numpy semantics)
// ---------------------------------------------------------------------------
__global__ __launch_bounds__(1024) void fps_kernel(const float* __restrict__ coords,
                                                   float* __restrict__ centers) {
#pragma clang fp contract(off)
    const int tid = threadIdx.x;
    float px[8], py[8], pz[8], dist[8];
#pragma unroll
    for (int i = 0; i < 8; ++i) {
        const int n = tid * 8 + i;
        px[i] = coords[n * 3 + 0];
        py[i] = coords[n * 3 + 1];
        pz[i] = coords[n * 3 + 2];
        dist[i] = 1e10f;
    }
    __shared__ float cur[3];
    __shared__ float wval[16];
    __shared__ int   widx[16];
    if (tid == 0) {
        cur[0] = coords[0]; cur[1] = coords[1]; cur[2] = coords[2];
        centers[0] = cur[0]; centers[1] = cur[1]; centers[2] = cur[2];
    }
    __syncthreads();
    for (int s = 1; s < KC; ++s) {
        const float cx = cur[0], cy = cur[1], cz = cur[2];
        float bv = -1.0f;
        int   bi = 0;
#pragma unroll
        for (int i = 0; i < 8; ++i) {
            const float dx = px[i] - cx;
            const float dy = py[i] - cy;
            const float dz = pz[i] - cz;
            const float d2 = (dx * dx + dy * dy) + dz * dz;
            const float dm = dist[i] < d2 ? dist[i] : d2;
            dist[i] = dm;
            if (dm > bv) { bv = dm; bi = tid * 8 + i; }  // strict > keeps lowest idx
        }
        // wave (64-lane) argmax reduce, tie -> lower index
#pragma unroll
        for (int off = 32; off > 0; off >>= 1) {
            const float ov = __shfl_down(bv, off);
            const int   oi = __shfl_down(bi, off);
            if (ov > bv || (ov == bv && oi < bi)) { bv = ov; bi = oi; }
        }
        const int wid = tid >> 6;
        if ((tid & 63) == 0) { wval[wid] = bv; widx[wid] = bi; }
        __syncthreads();
        if (tid == 0) {
            float fv = wval[0];
            int   fi = widx[0];
            for (int w = 1; w < 16; ++w) {
                if (wval[w] > fv || (wval[w] == fv && widx[w] < fi)) {
                    fv = wval[w]; fi = widx[w];
                }
            }
            const float x = coords[fi * 3 + 0];
            const float y = coords[fi * 3 + 1];
            const float z = coords[fi * 3 + 2];
            cur[0] = x; cur[1] = y; cur[2] = z;
            centers[s * 3 + 0] = x;
            centers[s * 3 + 1] = y;
            centers[s * 3 + 2] = z;
        }
        __syncthreads();
    }
}

// ---------------------------------------------------------------------------
// Kernel 2: F1[n][d] = b1[d] + sum_a features[n][a] * W1[3+a][d]
// (center-independent part of layer 1; rel-part added later)
// ---------------------------------------------------------------------------
__global__ __launch_bounds__(256) void feat_gemm_kernel(const float* __restrict__ features,
                                                        const float* __restrict__ W1,
                                                        const float* __restrict__ b1,
                                                        float* __restrict__ F1) {
    const int tid = threadIdx.x;
    const int d = tid & 63;
    const int p = blockIdx.x * 4 + (tid >> 6);
    float acc = b1[d];
    const float* frow = features + p * IFD;
    for (int a = 0; a < IFD; ++a) {
        acc += frow[a] * W1[(3 + a) * DL1 + d];
    }
    F1[p * DL1 + d] = acc;
}

// ---------------------------------------------------------------------------
// Kernel 3: per-center ball query + MLP + masked max
// grid = KC * SPLITS blocks of 256 threads; block handles PPB points of 1 center
// ---------------------------------------------------------------------------
__global__ __launch_bounds__(256) void group_mlp_kernel(
    const float* __restrict__ coords,
    const float* __restrict__ F1,
    const float* __restrict__ W1,   // rows 0..2 = rel part
    const float* __restrict__ W2,
    const float* __restrict__ b2,
    const float* __restrict__ W3,
    const float* __restrict__ b3,
    const float* __restrict__ centers,
    float* __restrict__ outf) {
    __shared__ float sW1r[3 * 64];
    __shared__ float sb2[64];
    __shared__ float sb3[128];
    __shared__ unsigned short list[PPB];
    __shared__ int cnt;
    __shared__ float h1[64 * 65];       // [point][dim], pad 65
    __shared__ float h2T[64 * 68];      // [dim][point], pad 68 (16B-aligned rows)
    __shared__ float red[8 * 128];

    const int tid = threadIdx.x;
    const int c = blockIdx.x >> 3;      // center id (SPLITS == 8)
    const int split = blockIdx.x & 7;
    const int base = split * PPB;

    if (tid < 192) sW1r[tid] = W1[tid];
    if (tid < 64)  sb2[tid] = b2[tid];
    if (tid < 128) sb3[tid] = b3[tid];
    if (tid == 0)  cnt = 0;
    const float cx = centers[c * 3 + 0];
    const float cy = centers[c * 3 + 1];
    const float cz = centers[c * 3 + 2];
    __syncthreads();

    // ---- ball-query compaction over this block's slice ----
    {
#pragma clang fp contract(off)
        for (int j = tid; j < PPB; j += 256) {
            const int n = base + j;
            const float dx = coords[n * 3 + 0] - cx;
            const float dy = coords[n * 3 + 1] - cy;
            const float dz = coords[n * 3 + 2] - cz;
            const float d2 = (dx * dx + dy * dy) + dz * dz;
            if (sqrtf(d2) < 1.0f) {
                const int pos = atomicAdd(&cnt, 1);
                list[pos] = (unsigned short)n;
            }
        }
    }
    __syncthreads();
    const int count = cnt;

    if (count > 0) {
        float rmax[4] = {0.f, 0.f, 0.f, 0.f};
        const int ntiles = (count + 63) >> 6;
        for (int T = 0; T < ntiles; ++T) {
            // ---- h1: [64 pts][64 dims], thread = (prow, d) ----
            {
                const int d = tid & 63;
                const int prow = tid >> 6;
#pragma unroll
                for (int r = 0; r < 16; ++r) {
                    const int p = r * 4 + prow;
                    const int li = T * 64 + p;
                    const int n = (li < count) ? (int)list[li] : (int)list[0];
                    const float rx = coords[n * 3 + 0] - cx;
                    const float ry = coords[n * 3 + 1] - cy;
                    const float rz = coords[n * 3 + 2] - cz;
                    float v = F1[n * DL1 + d];
                    v += rx * sW1r[d] + ry * sW1r[64 + d] + rz * sW1r[128 + d];
                    h1[p * 65 + d] = v > 0.f ? v : 0.f;
                }
            }
            __syncthreads();
            // ---- h2: 4x4 register blocks, output stored transposed ----
            {
                const int pblk = tid & 15;
                const int dblk = tid >> 4;
                const int p0 = pblk * 4;
                const int d0 = dblk * 4;
                float acc[4][4];
#pragma unroll
                for (int a = 0; a < 4; ++a)
#pragma unroll
                    for (int b = 0; b < 4; ++b) acc[a][b] = sb2[d0 + b];
                for (int i = 0; i < 64; ++i) {
                    float hv[4];
#pragma unroll
                    for (int a = 0; a < 4; ++a) hv[a] = h1[(p0 + a) * 65 + i];
                    const float4 w = *reinterpret_cast<const float4*>(&W2[i * DL2 + d0]);
#pragma unroll
                    for (int a = 0; a < 4; ++a) {
                        acc[a][0] += hv[a] * w.x;
                        acc[a][1] += hv[a] * w.y;
                        acc[a][2] += hv[a] * w.z;
                        acc[a][3] += hv[a] * w.w;
                    }
                }
#pragma unroll
                for (int b = 0; b < 4; ++b) {
                    float4 v;
                    v.x = fmaxf(acc[0][b], 0.f);
                    v.y = fmaxf(acc[1][b], 0.f);
                    v.z = fmaxf(acc[2][b], 0.f);
                    v.w = fmaxf(acc[3][b], 0.f);
                    *reinterpret_cast<float4*>(&h2T[(d0 + b) * 68 + p0]) = v;
                }
            }
            __syncthreads();
            // ---- h3: 8x4 register blocks + running max ----
            {
                const int dblk = tid & 31;
                const int pblk = tid >> 5;
                const int d0 = dblk * 4;
                const int p0 = pblk * 8;
                float acc[8][4];
#pragma unroll
                for (int p = 0; p < 8; ++p)
#pragma unroll
                    for (int b = 0; b < 4; ++b) acc[p][b] = sb3[d0 + b];
                for (int i = 0; i < 64; ++i) {
                    const float4 ha = *reinterpret_cast<const float4*>(&h2T[i * 68 + p0]);
                    const float4 hb = *reinterpret_cast<const float4*>(&h2T[i * 68 + p0 + 4]);
                    const float4 w = *reinterpret_cast<const float4*>(&W3[i * DL3 + d0]);
                    const float hv[8] = {ha.x, ha.y, ha.z, ha.w, hb.x, hb.y, hb.z, hb.w};
#pragma unroll
                    for (int p = 0; p < 8; ++p) {
                        acc[p][0] += hv[p] * w.x;
                        acc[p][1] += hv[p] * w.y;
                        acc[p][2] += hv[p] * w.z;
                        acc[p][3] += hv[p] * w.w;
                    }
                }
#pragma unroll
                for (int b = 0; b < 4; ++b) {
                    float m = acc[0][b];
#pragma unroll
                    for (int p = 1; p < 8; ++p) m = fmaxf(m, acc[p][b]);
                    m = fmaxf(m, 0.f);                 // relu (commutes with max)
                    rmax[b] = fmaxf(rmax[b], m);
                }
            }
            __syncthreads();
        }
        // ---- block reduce over the 8 point-groups, then global atomic max ----
        {
            const int dblk = tid & 31;
            const int pblk = tid >> 5;
            const int d0 = dblk * 4;
#pragma unroll
            for (int b = 0; b < 4; ++b) red[pblk * 128 + d0 + b] = rmax[b];
        }
        __syncthreads();
        if (tid < 128) {
            float m = red[tid];
#pragma unroll
            for (int r = 1; r < 8; ++r) m = fmaxf(m, red[r * 128 + tid]);
            atomicMax((int*)&outf[c * 128 + tid], __float_as_int(m));
        }
    }
}

// ---------------------------------------------------------------------------
extern "C" void kernel_launch(void* const* d_in, const int* in_sizes, int n_in,
                              void* d_out, int out_size, void* d_ws, size_t ws_size,
                              hipStream_t stream) {
    (void)in_sizes; (void)n_in; (void)ws_size;
    const float* coords   = (const float*)d_in[0];
    const float* features = (const float*)d_in[1];
    const float* W1 = (const float*)d_in[2];
    const float* b1 = (const float*)d_in[3];
    const float* W2 = (const float*)d_in[4];
    const float* b2 = (const float*)d_in[5];
    const float* W3 = (const float*)d_in[6];
    const float* b3 = (const float*)d_in[7];
    float* out = (float*)d_out;
    float* F1  = (float*)d_ws;   // 8192*64 floats = 2 MB scratch

    // out is re-poisoned before every launch; zero it (atomicMax identity, and
    // relu(h3) >= 0 so 0 is a safe floor matching max-over-nonempty-group).
    hipMemsetAsync(d_out, 0, (size_t)out_size * sizeof(float), stream);

    fps_kernel<<<1, 1024, 0, stream>>>(coords, out);
    feat_gemm_kernel<<<NPTS / 4, 256, 0, stream>>>(features, W1, b1, F1);
    group_mlp_kernel<<<KC * SPLITS, 256, 0, stream>>>(coords, F1, W1, W2, b2, W3, b3,
                                                      out, out + KC * 3);
}

// Round 3
// 375.062 us; speedup vs baseline: 1.1694x; 1.1694x over previous
//
#include <hip/hip_runtime.h>

#define NPTS 8192
#define KC   128
#define IFD  64
#define DL1  64
#define DL2  64
#define DL3  128
#define SPLITS 8
#define PPB  (NPTS/SPLITS)   // 1024 points per block

// ---------------------------------------------------------------------------
// Kernel 1 (fused): block 0 = farthest point sampling (serial-latency-optimized)
//                   blocks 1..2048 = F1 = features @ W1[3:] + b1  (independent)
// ---------------------------------------------------------------------------
__global__ __launch_bounds__(256) void fps_feat_kernel(
    const float* __restrict__ coords,
    const float* __restrict__ features,
    const float* __restrict__ W1,
    const float* __restrict__ b1,
    float* __restrict__ centers,
    float* __restrict__ F1) {
    const int tid = threadIdx.x;

    if (blockIdx.x != 0) {
        // ---- feature GEMM path: F1[p][d] = b1[d] + features[p] . W1[3:,d] ----
        const int d = tid & 63;
        const int p = (int)(blockIdx.x - 1) * 4 + (tid >> 6);
        float acc = b1[d];
        const float* frow = features + p * IFD;
#pragma unroll 8
        for (int a = 0; a < IFD; ++a) {
            acc += frow[a] * W1[(3 + a) * DL1 + d];
        }
        F1[p * DL1 + d] = acc;
        return;
    }

    // ---- FPS path: single block, 256 threads, 32 points/thread in registers --
    {
#pragma clang fp contract(off)
        float px[32], py[32], pz[32], dist[32];
#pragma unroll
        for (int i = 0; i < 32; ++i) {
            const int n = i * 256 + tid;
            px[i] = coords[n * 3 + 0];
            py[i] = coords[n * 3 + 1];
            pz[i] = coords[n * 3 + 2];
            dist[i] = 1e10f;
        }
        // double-buffered per-wave candidates: {val, x, y, z} + idx
        __shared__ float4 cand[2][4];
        __shared__ int    candi[2][4];

        float cx = coords[0], cy = coords[1], cz = coords[2];
        if (tid == 0) { centers[0] = cx; centers[1] = cy; centers[2] = cz; }

        for (int s = 1; s < KC; ++s) {
            float bv = -1.0f, bx = cx, by = cy, bz = cz;
            int   bi = 0;
#pragma unroll
            for (int i = 0; i < 32; ++i) {
                const float dx = px[i] - cx;
                const float dy = py[i] - cy;
                const float dz = pz[i] - cz;
                const float d2 = (dx * dx + dy * dy) + dz * dz;
                const float dm = dist[i] < d2 ? dist[i] : d2;
                dist[i] = dm;
                const bool win = dm > bv;      // strict > keeps lowest index
                bv = win ? dm : bv;
                bi = win ? i * 256 + tid : bi;
                bx = win ? px[i] : bx;
                by = win ? py[i] : by;
                bz = win ? pz[i] : bz;
            }
            // 64-lane argmax reduce carrying (val, idx, x, y, z); tie -> lower idx
#pragma unroll
            for (int off = 32; off > 0; off >>= 1) {
                const float ov = __shfl_down(bv, off);
                const int   oi = __shfl_down(bi, off);
                const float ox = __shfl_down(bx, off);
                const float oy = __shfl_down(by, off);
                const float oz = __shfl_down(bz, off);
                const bool take = (ov > bv) || (ov == bv && oi < bi);
                bv = take ? ov : bv;  bi = take ? oi : bi;
                bx = take ? ox : bx;  by = take ? oy : by;  bz = take ? oz : bz;
            }
            const int buf = s & 1;
            if ((tid & 63) == 0) {
                cand[buf][tid >> 6]  = make_float4(bv, bx, by, bz);
                candi[buf][tid >> 6] = bi;
            }
            __syncthreads();   // single barrier/iter; WAR on cand[buf] is covered
                               // by the NEXT iteration's barrier (double buffer)
            // every thread merges the 4 wave candidates redundantly (no broadcast)
            float4 c0 = cand[buf][0], c1 = cand[buf][1], c2 = cand[buf][2], c3 = cand[buf][3];
            int    i0 = candi[buf][0], i1 = candi[buf][1], i2 = candi[buf][2], i3 = candi[buf][3];
            float gv = c0.x; int gi = i0; float gx = c0.y, gy = c0.z, gz = c0.w;
            bool t;
            t = (c1.x > gv) || (c1.x == gv && i1 < gi);
            gv = t ? c1.x : gv; gi = t ? i1 : gi; gx = t ? c1.y : gx; gy = t ? c1.z : gy; gz = t ? c1.w : gz;
            t = (c2.x > gv) || (c2.x == gv && i2 < gi);
            gv = t ? c2.x : gv; gi = t ? i2 : gi; gx = t ? c2.y : gx; gy = t ? c2.z : gy; gz = t ? c2.w : gz;
            t = (c3.x > gv) || (c3.x == gv && i3 < gi);
            gv = t ? c3.x : gv; gi = t ? i3 : gi; gx = t ? c3.y : gx; gy = t ? c3.z : gy; gz = t ? c3.w : gz;

            cx = gx; cy = gy; cz = gz;
            if (tid == 0) {
                centers[s * 3 + 0] = gx;
                centers[s * 3 + 1] = gy;
                centers[s * 3 + 2] = gz;
            }
        }
    }
}

// ---------------------------------------------------------------------------
// Kernel 2: per-center ball query + MLP + masked max  (unchanged from R1)
// grid = KC * SPLITS blocks of 256 threads; block handles PPB points of 1 center
// ---------------------------------------------------------------------------
__global__ __launch_bounds__(256) void group_mlp_kernel(
    const float* __restrict__ coords,
    const float* __restrict__ F1,
    const float* __restrict__ W1,   // rows 0..2 = rel part
    const float* __restrict__ W2,
    const float* __restrict__ b2,
    const float* __restrict__ W3,
    const float* __restrict__ b3,
    const float* __restrict__ centers,
    float* __restrict__ outf) {
    __shared__ float sW1r[3 * 64];
    __shared__ float sb2[64];
    __shared__ float sb3[128];
    __shared__ unsigned short list[PPB];
    __shared__ int cnt;
    __shared__ float h1[64 * 65];       // [point][dim], pad 65
    __shared__ float h2T[64 * 68];      // [dim][point], pad 68 (16B-aligned rows)
    __shared__ float red[8 * 128];

    const int tid = threadIdx.x;
    const int c = blockIdx.x >> 3;      // center id (SPLITS == 8)
    const int split = blockIdx.x & 7;
    const int base = split * PPB;

    if (tid < 192) sW1r[tid] = W1[tid];
    if (tid < 64)  sb2[tid] = b2[tid];
    if (tid < 128) sb3[tid] = b3[tid];
    if (tid == 0)  cnt = 0;
    const float cx = centers[c * 3 + 0];
    const float cy = centers[c * 3 + 1];
    const float cz = centers[c * 3 + 2];
    __syncthreads();

    // ---- ball-query compaction over this block's slice ----
    {
#pragma clang fp contract(off)
        for (int j = tid; j < PPB; j += 256) {
            const int n = base + j;
            const float dx = coords[n * 3 + 0] - cx;
            const float dy = coords[n * 3 + 1] - cy;
            const float dz = coords[n * 3 + 2] - cz;
            const float d2 = (dx * dx + dy * dy) + dz * dz;
            if (sqrtf(d2) < 1.0f) {
                const int pos = atomicAdd(&cnt, 1);
                list[pos] = (unsigned short)n;
            }
        }
    }
    __syncthreads();
    const int count = cnt;

    if (count > 0) {
        float rmax[4] = {0.f, 0.f, 0.f, 0.f};
        const int ntiles = (count + 63) >> 6;
        for (int T = 0; T < ntiles; ++T) {
            // ---- h1: [64 pts][64 dims], thread = (prow, d) ----
            {
                const int d = tid & 63;
                const int prow = tid >> 6;
#pragma unroll
                for (int r = 0; r < 16; ++r) {
                    const int p = r * 4 + prow;
                    const int li = T * 64 + p;
                    const int n = (li < count) ? (int)list[li] : (int)list[0];
                    const float rx = coords[n * 3 + 0] - cx;
                    const float ry = coords[n * 3 + 1] - cy;
                    const float rz = coords[n * 3 + 2] - cz;
                    float v = F1[n * DL1 + d];
                    v += rx * sW1r[d] + ry * sW1r[64 + d] + rz * sW1r[128 + d];
                    h1[p * 65 + d] = v > 0.f ? v : 0.f;
                }
            }
            __syncthreads();
            // ---- h2: 4x4 register blocks, output stored transposed ----
            {
                const int pblk = tid & 15;
                const int dblk = tid >> 4;
                const int p0 = pblk * 4;
                const int d0 = dblk * 4;
                float acc[4][4];
#pragma unroll
                for (int a = 0; a < 4; ++a)
#pragma unroll
                    for (int b = 0; b < 4; ++b) acc[a][b] = sb2[d0 + b];
                for (int i = 0; i < 64; ++i) {
                    float hv[4];
#pragma unroll
                    for (int a = 0; a < 4; ++a) hv[a] = h1[(p0 + a) * 65 + i];
                    const float4 w = *reinterpret_cast<const float4*>(&W2[i * DL2 + d0]);
#pragma unroll
                    for (int a = 0; a < 4; ++a) {
                        acc[a][0] += hv[a] * w.x;
                        acc[a][1] += hv[a] * w.y;
                        acc[a][2] += hv[a] * w.z;
                        acc[a][3] += hv[a] * w.w;
                    }
                }
#pragma unroll
                for (int b = 0; b < 4; ++b) {
                    float4 v;
                    v.x = fmaxf(acc[0][b], 0.f);
                    v.y = fmaxf(acc[1][b], 0.f);
                    v.z = fmaxf(acc[2][b], 0.f);
                    v.w = fmaxf(acc[3][b], 0.f);
                    *reinterpret_cast<float4*>(&h2T[(d0 + b) * 68 + p0]) = v;
                }
            }
            __syncthreads();
            // ---- h3: 8x4 register blocks + running max ----
            {
                const int dblk = tid & 31;
                const int pblk = tid >> 5;
                const int d0 = dblk * 4;
                const int p0 = pblk * 8;
                float acc[8][4];
#pragma unroll
                for (int p = 0; p < 8; ++p)
#pragma unroll
                    for (int b = 0; b < 4; ++b) acc[p][b] = sb3[d0 + b];
                for (int i = 0; i < 64; ++i) {
                    const float4 ha = *reinterpret_cast<const float4*>(&h2T[i * 68 + p0]);
                    const float4 hb = *reinterpret_cast<const float4*>(&h2T[i * 68 + p0 + 4]);
                    const float4 w = *reinterpret_cast<const float4*>(&W3[i * DL3 + d0]);
                    const float hv[8] = {ha.x, ha.y, ha.z, ha.w, hb.x, hb.y, hb.z, hb.w};
#pragma unroll
                    for (int p = 0; p < 8; ++p) {
                        acc[p][0] += hv[p] * w.x;
                        acc[p][1] += hv[p] * w.y;
                        acc[p][2] += hv[p] * w.z;
                        acc[p][3] += hv[p] * w.w;
                    }
                }
#pragma unroll
                for (int b = 0; b < 4; ++b) {
                    float m = acc[0][b];
#pragma unroll
                    for (int p = 1; p < 8; ++p) m = fmaxf(m, acc[p][b]);
                    m = fmaxf(m, 0.f);                 // relu (commutes with max)
                    rmax[b] = fmaxf(rmax[b], m);
                }
            }
            __syncthreads();
        }
        // ---- block reduce over the 8 point-groups, then global atomic max ----
        {
            const int dblk = tid & 31;
            const int pblk = tid >> 5;
            const int d0 = dblk * 4;
#pragma unroll
            for (int b = 0; b < 4; ++b) red[pblk * 128 + d0 + b] = rmax[b];
        }
        __syncthreads();
        if (tid < 128) {
            float m = red[tid];
#pragma unroll
            for (int r = 1; r < 8; ++r) m = fmaxf(m, red[r * 128 + tid]);
            atomicMax((int*)&outf[c * 128 + tid], __float_as_int(m));
        }
    }
}

// ---------------------------------------------------------------------------
extern "C" void kernel_launch(void* const* d_in, const int* in_sizes, int n_in,
                              void* d_out, int out_size, void* d_ws, size_t ws_size,
                              hipStream_t stream) {
    (void)in_sizes; (void)n_in; (void)ws_size;
    const float* coords   = (const float*)d_in[0];
    const float* features = (const float*)d_in[1];
    const float* W1 = (const float*)d_in[2];
    const float* b1 = (const float*)d_in[3];
    const float* W2 = (const float*)d_in[4];
    const float* b2 = (const float*)d_in[5];
    const float* W3 = (const float*)d_in[6];
    const float* b3 = (const float*)d_in[7];
    float* out = (float*)d_out;
    float* F1  = (float*)d_ws;   // 8192*64 floats = 2 MB scratch

    // out is re-poisoned before every launch; zero it (atomicMax identity, and
    // relu(h3) >= 0 so 0 is a safe floor matching max-over-nonempty-group).
    (void)hipMemsetAsync(d_out, 0, (size_t)out_size * sizeof(float), stream);

    // block 0: FPS (single CU, serial); blocks 1..2048: F1 precompute (other CUs)
    fps_feat_kernel<<<1 + NPTS / 4, 256, 0, stream>>>(coords, features, W1, b1,
                                                      out, F1);
    group_mlp_kernel<<<KC * SPLITS, 256, 0, stream>>>(coords, F1, W1, W2, b2, W3, b3,
                                                      out, out + KC * 3);
}

// Round 4
// 258.848 us; speedup vs baseline: 1.6944x; 1.4490x over previous
//
#include <hip/hip_runtime.h>

#define NPTS 8192
#define KC   128
#define IFD  64
#define DL1  64
#define DL2  64
#define DL3  128
#define SPLITS 8
#define PPB  (NPTS/SPLITS)   // 1024 points per block (group_mlp)
#define FPT  16              // FPS points per thread (512 threads)

// ---------------------------------------------------------------------------
// Kernel 1 (fused): block 0 = farthest point sampling (serial-latency-optimized)
//                   blocks 1..1024 = F1 = features @ W1[3:] + b1  (independent)
// ---------------------------------------------------------------------------
__global__ __launch_bounds__(512, 2) void fps_feat_kernel(
    const float* __restrict__ coords,
    const float* __restrict__ features,
    const float* __restrict__ W1,
    const float* __restrict__ b1,
    float* __restrict__ centers,
    float* __restrict__ F1) {
    const int tid = threadIdx.x;

    if (blockIdx.x != 0) {
        // ---- feature GEMM path: F1[p][d] = b1[d] + features[p] . W1[3:,d] ----
        const int d = tid & 63;
        const int p = (int)(blockIdx.x - 1) * 8 + (tid >> 6);
        float acc = b1[d];
        const float* frow = features + p * IFD;
#pragma unroll 8
        for (int a = 0; a < IFD; ++a) {
            acc += frow[a] * W1[(3 + a) * DL1 + d];
        }
        F1[p * DL1 + d] = acc;
        return;
    }

    // ---- FPS path: single block, 512 threads, 16 points/thread in registers --
    {
#pragma clang fp contract(off)
        float px[FPT], py[FPT], pz[FPT], dist[FPT];
#pragma unroll
        for (int i = 0; i < FPT; ++i) {
            const int n = i * 512 + tid;
            px[i] = coords[n * 3 + 0];
            py[i] = coords[n * 3 + 1];
            pz[i] = coords[n * 3 + 2];
            dist[i] = 1e10f;
        }
        __shared__ float wv[2][8];   // per-wave max value, double-buffered
        __shared__ int   widx[2];    // argmax index (atomicMin), double-buffered

        if (tid == 0) { widx[0] = 0x7FFFFFFF; widx[1] = 0x7FFFFFFF; }

        float cx = coords[0], cy = coords[1], cz = coords[2];
        if (tid == 0) { centers[0] = cx; centers[1] = cy; centers[2] = cz; }
        __syncthreads();

        for (int s = 1; s < KC; ++s) {
            const int buf = s & 1;
            // --- distance update + value-only max (10 VALU ops / point) ---
            float bv = -1.0f;
#pragma unroll
            for (int i = 0; i < FPT; ++i) {
                const float dx = px[i] - cx;
                const float dy = py[i] - cy;
                const float dz = pz[i] - cz;
                const float d2 = (dx * dx + dy * dy) + dz * dz;
                const float dm = dist[i] < d2 ? dist[i] : d2;   // v_min_f32
                dist[i] = dm;
                bv = fmaxf(bv, dm);
            }
            // --- wave value-max reduce (max is exactly associative) ---
#pragma unroll
            for (int off = 32; off > 0; off >>= 1) {
                bv = fmaxf(bv, __shfl_down(bv, off));
            }
            if ((tid & 63) == 0) wv[buf][tid >> 6] = bv;
            __syncthreads();                       // barrier 1
            // --- all threads merge the 8 wave maxima ---
            float gv = wv[buf][0];
#pragma unroll
            for (int w = 1; w < 8; ++w) gv = fmaxf(gv, wv[buf][w]);
            // --- index recovery: lowest global index with dist == gv ---
            int ln = 0x7FFFFFFF;
#pragma unroll
            for (int i = 0; i < FPT; ++i) {
                if (dist[i] == gv) ln = min(ln, i * 512 + tid);
            }
            if (ln != 0x7FFFFFFF) atomicMin(&widx[buf], ln);
            __syncthreads();                       // barrier 2
            const int w = widx[buf];
            if (tid == 0) widx[buf ^ 1] = 0x7FFFFFFF;  // re-arm other buffer
            // --- uniform broadcast load of the winner's coords ---
            cx = coords[w * 3 + 0];
            cy = coords[w * 3 + 1];
            cz = coords[w * 3 + 2];
            if (tid == 0) {
                centers[s * 3 + 0] = cx;
                centers[s * 3 + 1] = cy;
                centers[s * 3 + 2] = cz;
            }
        }
    }
}

// ---------------------------------------------------------------------------
// Kernel 2: per-center ball query + MLP + masked max  (unchanged)
// grid = KC * SPLITS blocks of 256 threads; block handles PPB points of 1 center
// ---------------------------------------------------------------------------
__global__ __launch_bounds__(256) void group_mlp_kernel(
    const float* __restrict__ coords,
    const float* __restrict__ F1,
    const float* __restrict__ W1,   // rows 0..2 = rel part
    const float* __restrict__ W2,
    const float* __restrict__ b2,
    const float* __restrict__ W3,
    const float* __restrict__ b3,
    const float* __restrict__ centers,
    float* __restrict__ outf) {
    __shared__ float sW1r[3 * 64];
    __shared__ float sb2[64];
    __shared__ float sb3[128];
    __shared__ unsigned short list[PPB];
    __shared__ int cnt;
    __shared__ float h1[64 * 65];       // [point][dim], pad 65
    __shared__ float h2T[64 * 68];      // [dim][point], pad 68 (16B-aligned rows)
    __shared__ float red[8 * 128];

    const int tid = threadIdx.x;
    const int c = blockIdx.x >> 3;      // center id (SPLITS == 8)
    const int split = blockIdx.x & 7;
    const int base = split * PPB;

    if (tid < 192) sW1r[tid] = W1[tid];
    if (tid < 64)  sb2[tid] = b2[tid];
    if (tid < 128) sb3[tid] = b3[tid];
    if (tid == 0)  cnt = 0;
    const float cx = centers[c * 3 + 0];
    const float cy = centers[c * 3 + 1];
    const float cz = centers[c * 3 + 2];
    __syncthreads();

    // ---- ball-query compaction over this block's slice ----
    {
#pragma clang fp contract(off)
        for (int j = tid; j < PPB; j += 256) {
            const int n = base + j;
            const float dx = coords[n * 3 + 0] - cx;
            const float dy = coords[n * 3 + 1] - cy;
            const float dz = coords[n * 3 + 2] - cz;
            const float d2 = (dx * dx + dy * dy) + dz * dz;
            if (sqrtf(d2) < 1.0f) {
                const int pos = atomicAdd(&cnt, 1);
                list[pos] = (unsigned short)n;
            }
        }
    }
    __syncthreads();
    const int count = cnt;

    if (count > 0) {
        float rmax[4] = {0.f, 0.f, 0.f, 0.f};
        const int ntiles = (count + 63) >> 6;
        for (int T = 0; T < ntiles; ++T) {
            // ---- h1: [64 pts][64 dims], thread = (prow, d) ----
            {
                const int d = tid & 63;
                const int prow = tid >> 6;
#pragma unroll
                for (int r = 0; r < 16; ++r) {
                    const int p = r * 4 + prow;
                    const int li = T * 64 + p;
                    const int n = (li < count) ? (int)list[li] : (int)list[0];
                    const float rx = coords[n * 3 + 0] - cx;
                    const float ry = coords[n * 3 + 1] - cy;
                    const float rz = coords[n * 3 + 2] - cz;
                    float v = F1[n * DL1 + d];
                    v += rx * sW1r[d] + ry * sW1r[64 + d] + rz * sW1r[128 + d];
                    h1[p * 65 + d] = v > 0.f ? v : 0.f;
                }
            }
            __syncthreads();
            // ---- h2: 4x4 register blocks, output stored transposed ----
            {
                const int pblk = tid & 15;
                const int dblk = tid >> 4;
                const int p0 = pblk * 4;
                const int d0 = dblk * 4;
                float acc[4][4];
#pragma unroll
                for (int a = 0; a < 4; ++a)
#pragma unroll
                    for (int b = 0; b < 4; ++b) acc[a][b] = sb2[d0 + b];
                for (int i = 0; i < 64; ++i) {
                    float hv[4];
#pragma unroll
                    for (int a = 0; a < 4; ++a) hv[a] = h1[(p0 + a) * 65 + i];
                    const float4 w = *reinterpret_cast<const float4*>(&W2[i * DL2 + d0]);
#pragma unroll
                    for (int a = 0; a < 4; ++a) {
                        acc[a][0] += hv[a] * w.x;
                        acc[a][1] += hv[a] * w.y;
                        acc[a][2] += hv[a] * w.z;
                        acc[a][3] += hv[a] * w.w;
                    }
                }
#pragma unroll
                for (int b = 0; b < 4; ++b) {
                    float4 v;
                    v.x = fmaxf(acc[0][b], 0.f);
                    v.y = fmaxf(acc[1][b], 0.f);
                    v.z = fmaxf(acc[2][b], 0.f);
                    v.w = fmaxf(acc[3][b], 0.f);
                    *reinterpret_cast<float4*>(&h2T[(d0 + b) * 68 + p0]) = v;
                }
            }
            __syncthreads();
            // ---- h3: 8x4 register blocks + running max ----
            {
                const int dblk = tid & 31;
                const int pblk = tid >> 5;
                const int d0 = dblk * 4;
                const int p0 = pblk * 8;
                float acc[8][4];
#pragma unroll
                for (int p = 0; p < 8; ++p)
#pragma unroll
                    for (int b = 0; b < 4; ++b) acc[p][b] = sb3[d0 + b];
                for (int i = 0; i < 64; ++i) {
                    const float4 ha = *reinterpret_cast<const float4*>(&h2T[i * 68 + p0]);
                    const float4 hb = *reinterpret_cast<const float4*>(&h2T[i * 68 + p0 + 4]);
                    const float4 w = *reinterpret_cast<const float4*>(&W3[i * DL3 + d0]);
                    const float hv[8] = {ha.x, ha.y, ha.z, ha.w, hb.x, hb.y, hb.z, hb.w};
#pragma unroll
                    for (int p = 0; p < 8; ++p) {
                        acc[p][0] += hv[p] * w.x;
                        acc[p][1] += hv[p] * w.y;
                        acc[p][2] += hv[p] * w.z;
                        acc[p][3] += hv[p] * w.w;
                    }
                }
#pragma unroll
                for (int b = 0; b < 4; ++b) {
                    float m = acc[0][b];
#pragma unroll
                    for (int p = 1; p < 8; ++p) m = fmaxf(m, acc[p][b]);
                    m = fmaxf(m, 0.f);                 // relu (commutes with max)
                    rmax[b] = fmaxf(rmax[b], m);
                }
            }
            __syncthreads();
        }
        // ---- block reduce over the 8 point-groups, then global atomic max ----
        {
            const int dblk = tid & 31;
            const int pblk = tid >> 5;
            const int d0 = dblk * 4;
#pragma unroll
            for (int b = 0; b < 4; ++b) red[pblk * 128 + d0 + b] = rmax[b];
        }
        __syncthreads();
        if (tid < 128) {
            float m = red[tid];
#pragma unroll
            for (int r = 1; r < 8; ++r) m = fmaxf(m, red[r * 128 + tid]);
            atomicMax((int*)&outf[c * 128 + tid], __float_as_int(m));
        }
    }
}

// ---------------------------------------------------------------------------
extern "C" void kernel_launch(void* const* d_in, const int* in_sizes, int n_in,
                              void* d_out, int out_size, void* d_ws, size_t ws_size,
                              hipStream_t stream) {
    (void)in_sizes; (void)n_in; (void)ws_size;
    const float* coords   = (const float*)d_in[0];
    const float* features = (const float*)d_in[1];
    const float* W1 = (const float*)d_in[2];
    const float* b1 = (const float*)d_in[3];
    const float* W2 = (const float*)d_in[4];
    const float* b2 = (const float*)d_in[5];
    const float* W3 = (const float*)d_in[6];
    const float* b3 = (const float*)d_in[7];
    float* out = (float*)d_out;
    float* F1  = (float*)d_ws;   // 8192*64 floats = 2 MB scratch

    // out is re-poisoned before every launch; zero it (atomicMax identity, and
    // relu(h3) >= 0 so 0 is a safe floor matching max-over-nonempty-group).
    (void)hipMemsetAsync(d_out, 0, (size_t)out_size * sizeof(float), stream);

    // block 0: FPS (single CU, serial); blocks 1..1024: F1 precompute (other CUs)
    fps_feat_kernel<<<1 + NPTS / 8, 512, 0, stream>>>(coords, features, W1, b1,
                                                      out, F1);
    group_mlp_kernel<<<KC * SPLITS, 256, 0, stream>>>(coords, F1, W1, W2, b2, W3, b3,
                                                      out, out + KC * 3);
}

// Round 5
// 257.902 us; speedup vs baseline: 1.7006x; 1.0037x over previous
//
#include <hip/hip_runtime.h>

#define NPTS 8192
#define KC   128
#define IFD  64
#define DL1  64
#define DL2  64
#define DL3  128
#define SPLITS 8
#define PPB  (NPTS/SPLITS)   // 1024 points per block (group_mlp)

// X-macro over the 16 per-thread FPS points -> named scalars (NO allocas, so
// state cannot be demoted to scratch; R1/R3/R4 all show float[] allocas land
// in scratch: VGPR_Count 32/128/48 < state size, ~2850 cyc/iter of spill traffic)
#define FOR16(F) F(0) F(1) F(2) F(3) F(4) F(5) F(6) F(7) \
                 F(8) F(9) F(10) F(11) F(12) F(13) F(14) F(15)

// ---------------------------------------------------------------------------
// Kernel 1 (fused): block 0 = farthest point sampling (serial-latency-optimized)
//                   blocks 1..1024 = F1 = features @ W1[3:] + b1  (independent)
// ---------------------------------------------------------------------------
__global__ __launch_bounds__(512) void fps_feat_kernel(
    const float* __restrict__ coords,
    const float* __restrict__ features,
    const float* __restrict__ W1,
    const float* __restrict__ b1,
    float* __restrict__ centers,
    float* __restrict__ F1) {
    const int tid = threadIdx.x;

    if (blockIdx.x != 0) {
        // ---- feature GEMM path: F1[p][d] = b1[d] + features[p] . W1[3:,d] ----
        const int d = tid & 63;
        const int p = (int)(blockIdx.x - 1) * 8 + (tid >> 6);
        float acc = b1[d];
        const float* frow = features + p * IFD;
#pragma unroll 8
        for (int a = 0; a < IFD; ++a) {
            acc += frow[a] * W1[(3 + a) * DL1 + d];
        }
        F1[p * DL1 + d] = acc;
        return;
    }

    // ---- FPS path: single block, 512 threads, 16 points/thread in registers --
    {
#pragma clang fp contract(off)
#define FPS_DECL(i) float x##i, y##i, z##i, d##i = 1e10f;
        FOR16(FPS_DECL)
#define FPS_LOAD(i) { const int n = i * 512 + tid; \
                      x##i = coords[n * 3 + 0];    \
                      y##i = coords[n * 3 + 1];    \
                      z##i = coords[n * 3 + 2]; }
        FOR16(FPS_LOAD)

        __shared__ float wv[2][8];   // per-wave max value, double-buffered
        __shared__ int   widx[2];    // argmax index (atomicMin), double-buffered

        if (tid == 0) { widx[0] = 0x7FFFFFFF; widx[1] = 0x7FFFFFFF; }

        float cx = coords[0], cy = coords[1], cz = coords[2];
        if (tid == 0) { centers[0] = cx; centers[1] = cy; centers[2] = cz; }
        __syncthreads();

        for (int s = 1; s < KC; ++s) {
            const int buf = s & 1;
            // --- distance update + value-only max (10 VALU ops / point) ---
            float bv = -1.0f;
#define FPS_UPD(i) { const float dx = x##i - cx;              \
                     const float dy = y##i - cy;              \
                     const float dz = z##i - cz;              \
                     const float t2 = (dx * dx + dy * dy) + dz * dz; \
                     d##i = d##i < t2 ? d##i : t2;            \
                     bv = fmaxf(bv, d##i); }
            FOR16(FPS_UPD)
            // --- wave value-max reduce (max is exactly associative) ---
#pragma unroll
            for (int off = 32; off > 0; off >>= 1) {
                bv = fmaxf(bv, __shfl_down(bv, off));
            }
            if ((tid & 63) == 0) wv[buf][tid >> 6] = bv;
            __syncthreads();                       // barrier 1
            // --- all threads merge the 8 wave maxima ---
            float gv = wv[buf][0];
#pragma unroll
            for (int w = 1; w < 8; ++w) gv = fmaxf(gv, wv[buf][w]);
            // --- index recovery: lowest global index with dist == gv ---
            int ln = 0x7FFFFFFF;
#define FPS_CHK(i) if (d##i == gv) ln = min(ln, i * 512 + tid);
            FOR16(FPS_CHK)
            if (ln != 0x7FFFFFFF) atomicMin(&widx[buf], ln);
            __syncthreads();                       // barrier 2
            const int w = widx[buf];
            if (tid == 0) widx[buf ^ 1] = 0x7FFFFFFF;  // re-arm other buffer
            // --- uniform broadcast load of the winner's coords ---
            cx = coords[w * 3 + 0];
            cy = coords[w * 3 + 1];
            cz = coords[w * 3 + 2];
            if (tid == 0) {
                centers[s * 3 + 0] = cx;
                centers[s * 3 + 1] = cy;
                centers[s * 3 + 2] = cz;
            }
        }
    }
}

// ---------------------------------------------------------------------------
// Kernel 2: per-center ball query + MLP + masked max  (unchanged)
// grid = KC * SPLITS blocks of 256 threads; block handles PPB points of 1 center
// ---------------------------------------------------------------------------
__global__ __launch_bounds__(256) void group_mlp_kernel(
    const float* __restrict__ coords,
    const float* __restrict__ F1,
    const float* __restrict__ W1,   // rows 0..2 = rel part
    const float* __restrict__ W2,
    const float* __restrict__ b2,
    const float* __restrict__ W3,
    const float* __restrict__ b3,
    const float* __restrict__ centers,
    float* __restrict__ outf) {
    __shared__ float sW1r[3 * 64];
    __shared__ float sb2[64];
    __shared__ float sb3[128];
    __shared__ unsigned short list[PPB];
    __shared__ int cnt;
    __shared__ float h1[64 * 65];       // [point][dim], pad 65
    __shared__ float h2T[64 * 68];      // [dim][point], pad 68 (16B-aligned rows)
    __shared__ float red[8 * 128];

    const int tid = threadIdx.x;
    const int c = blockIdx.x >> 3;      // center id (SPLITS == 8)
    const int split = blockIdx.x & 7;
    const int base = split * PPB;

    if (tid < 192) sW1r[tid] = W1[tid];
    if (tid < 64)  sb2[tid] = b2[tid];
    if (tid < 128) sb3[tid] = b3[tid];
    if (tid == 0)  cnt = 0;
    const float cx = centers[c * 3 + 0];
    const float cy = centers[c * 3 + 1];
    const float cz = centers[c * 3 + 2];
    __syncthreads();

    // ---- ball-query compaction over this block's slice ----
    {
#pragma clang fp contract(off)
        for (int j = tid; j < PPB; j += 256) {
            const int n = base + j;
            const float dx = coords[n * 3 + 0] - cx;
            const float dy = coords[n * 3 + 1] - cy;
            const float dz = coords[n * 3 + 2] - cz;
            const float d2 = (dx * dx + dy * dy) + dz * dz;
            if (sqrtf(d2) < 1.0f) {
                const int pos = atomicAdd(&cnt, 1);
                list[pos] = (unsigned short)n;
            }
        }
    }
    __syncthreads();
    const int count = cnt;

    if (count > 0) {
        float rmax[4] = {0.f, 0.f, 0.f, 0.f};
        const int ntiles = (count + 63) >> 6;
        for (int T = 0; T < ntiles; ++T) {
            // ---- h1: [64 pts][64 dims], thread = (prow, d) ----
            {
                const int d = tid & 63;
                const int prow = tid >> 6;
#pragma unroll
                for (int r = 0; r < 16; ++r) {
                    const int p = r * 4 + prow;
                    const int li = T * 64 + p;
                    const int n = (li < count) ? (int)list[li] : (int)list[0];
                    const float rx = coords[n * 3 + 0] - cx;
                    const float ry = coords[n * 3 + 1] - cy;
                    const float rz = coords[n * 3 + 2] - cz;
                    float v = F1[n * DL1 + d];
                    v += rx * sW1r[d] + ry * sW1r[64 + d] + rz * sW1r[128 + d];
                    h1[p * 65 + d] = v > 0.f ? v : 0.f;
                }
            }
            __syncthreads();
            // ---- h2: 4x4 register blocks, output stored transposed ----
            {
                const int pblk = tid & 15;
                const int dblk = tid >> 4;
                const int p0 = pblk * 4;
                const int d0 = dblk * 4;
                float acc[4][4];
#pragma unroll
                for (int a = 0; a < 4; ++a)
#pragma unroll
                    for (int b = 0; b < 4; ++b) acc[a][b] = sb2[d0 + b];
                for (int i = 0; i < 64; ++i) {
                    float hv[4];
#pragma unroll
                    for (int a = 0; a < 4; ++a) hv[a] = h1[(p0 + a) * 65 + i];
                    const float4 w = *reinterpret_cast<const float4*>(&W2[i * DL2 + d0]);
#pragma unroll
                    for (int a = 0; a < 4; ++a) {
                        acc[a][0] += hv[a] * w.x;
                        acc[a][1] += hv[a] * w.y;
                        acc[a][2] += hv[a] * w.z;
                        acc[a][3] += hv[a] * w.w;
                    }
                }
#pragma unroll
                for (int b = 0; b < 4; ++b) {
                    float4 v;
                    v.x = fmaxf(acc[0][b], 0.f);
                    v.y = fmaxf(acc[1][b], 0.f);
                    v.z = fmaxf(acc[2][b], 0.f);
                    v.w = fmaxf(acc[3][b], 0.f);
                    *reinterpret_cast<float4*>(&h2T[(d0 + b) * 68 + p0]) = v;
                }
            }
            __syncthreads();
            // ---- h3: 8x4 register blocks + running max ----
            {
                const int dblk = tid & 31;
                const int pblk = tid >> 5;
                const int d0 = dblk * 4;
                const int p0 = pblk * 8;
                float acc[8][4];
#pragma unroll
                for (int p = 0; p < 8; ++p)
#pragma unroll
                    for (int b = 0; b < 4; ++b) acc[p][b] = sb3[d0 + b];
                for (int i = 0; i < 64; ++i) {
                    const float4 ha = *reinterpret_cast<const float4*>(&h2T[i * 68 + p0]);
                    const float4 hb = *reinterpret_cast<const float4*>(&h2T[i * 68 + p0 + 4]);
                    const float4 w = *reinterpret_cast<const float4*>(&W3[i * DL3 + d0]);
                    const float hv[8] = {ha.x, ha.y, ha.z, ha.w, hb.x, hb.y, hb.z, hb.w};
#pragma unroll
                    for (int p = 0; p < 8; ++p) {
                        acc[p][0] += hv[p] * w.x;
                        acc[p][1] += hv[p] * w.y;
                        acc[p][2] += hv[p] * w.z;
                        acc[p][3] += hv[p] * w.w;
                    }
                }
#pragma unroll
                for (int b = 0; b < 4; ++b) {
                    float m = acc[0][b];
#pragma unroll
                    for (int p = 1; p < 8; ++p) m = fmaxf(m, acc[p][b]);
                    m = fmaxf(m, 0.f);                 // relu (commutes with max)
                    rmax[b] = fmaxf(rmax[b], m);
                }
            }
            __syncthreads();
        }
        // ---- block reduce over the 8 point-groups, then global atomic max ----
        {
            const int dblk = tid & 31;
            const int pblk = tid >> 5;
            const int d0 = dblk * 4;
#pragma unroll
            for (int b = 0; b < 4; ++b) red[pblk * 128 + d0 + b] = rmax[b];
        }
        __syncthreads();
        if (tid < 128) {
            float m = red[tid];
#pragma unroll
            for (int r = 1; r < 8; ++r) m = fmaxf(m, red[r * 128 + tid]);
            atomicMax((int*)&outf[c * 128 + tid], __float_as_int(m));
        }
    }
}

// ---------------------------------------------------------------------------
extern "C" void kernel_launch(void* const* d_in, const int* in_sizes, int n_in,
                              void* d_out, int out_size, void* d_ws, size_t ws_size,
                              hipStream_t stream) {
    (void)in_sizes; (void)n_in; (void)ws_size;
    const float* coords   = (const float*)d_in[0];
    const float* features = (const float*)d_in[1];
    const float* W1 = (const float*)d_in[2];
    const float* b1 = (const float*)d_in[3];
    const float* W2 = (const float*)d_in[4];
    const float* b2 = (const float*)d_in[5];
    const float* W3 = (const float*)d_in[6];
    const float* b3 = (const float*)d_in[7];
    float* out = (float*)d_out;
    float* F1  = (float*)d_ws;   // 8192*64 floats = 2 MB scratch

    // out is re-poisoned before every launch; zero it (atomicMax identity, and
    // relu(h3) >= 0 so 0 is a safe floor matching max-over-nonempty-group).
    (void)hipMemsetAsync(d_out, 0, (size_t)out_size * sizeof(float), stream);

    // block 0: FPS (single CU, serial); blocks 1..1024: F1 precompute (other CUs)
    fps_feat_kernel<<<1 + NPTS / 8, 512, 0, stream>>>(coords, features, W1, b1,
                                                      out, F1);
    group_mlp_kernel<<<KC * SPLITS, 256, 0, stream>>>(coords, F1, W1, W2, b2, W3, b3,
                                                      out, out + KC * 3);
}